// Round 8
// baseline (71.108 us; speedup 1.0000x reference)
//
#include <hip/hip_runtime.h>
#include <math.h>

#define N 2
#define C 19
#define H 512
#define W 512
#define PADC 50
#define WC 412
#define S 8192
#define CP 20            // fp32 P row pitch (floats)
#define XP 64            // packed row pitch (ushorts): two 32-slot K-vectors
#define NCHUNK 16
#define CHUNKT (S / NCHUNK)      // 512 t per chunk
#define TTS 128                  // t rows per LDS stage
#define NSTG (CHUNKT / TTS)      // 4
#define TPS (TTS / 32)           // tiles per stage = 4
#define LPITCH 72                // ushorts per LDS row (144 B)
#define NBLK ((N * S) / 8)       // refine_loss blocks = 2048
#define EPSF 1e-6f

typedef __attribute__((ext_vector_type(8))) short short8;
typedef __attribute__((ext_vector_type(16))) float f32x16;

__device__ __forceinline__ unsigned short f2bf_rne(float x) {
    unsigned u = __float_as_uint(x);
    unsigned r = (u + 0x7FFFu + ((u >> 16) & 1u)) >> 16;
    return (unsigned short)r;
}
__device__ __forceinline__ float bf2f(unsigned short h) {
    return __uint_as_float(((unsigned)h) << 16);
}
// max of 16 accs, clamped >= 0; max3-shaped
__device__ __forceinline__ float max16c(const f32x16 a) {
    float m0 = fmaxf(fmaxf(a[0], a[1]), a[2]);
    float m1 = fmaxf(fmaxf(a[3], a[4]), a[5]);
    float m2 = fmaxf(fmaxf(a[6], a[7]), a[8]);
    float m3 = fmaxf(fmaxf(a[9], a[10]), a[11]);
    float m4 = fmaxf(fmaxf(a[12], a[13]), a[14]);
    float n0 = fmaxf(fmaxf(m0, m1), m2);
    float n1 = fmaxf(fmaxf(m3, m4), a[15]);
    return fmaxf(fmaxf(n0, n1), 0.f);
}

// P32: exact fp32 rows. XA/XB: packed split-precision K=2x32 layouts so that
// slot-wise A*B gives hi.hi(19) + hi.lo(19) + lo.hi(19) (57 products in 64 slots):
//  A row: [hi(0..18), lo(0..12) | hi(0..18), lo(13..18), 0*7]
//  B row: [hi(0..18), hi(0..12) | lo(0..18), hi(13..18), 0*7]
__global__ void gather_k(const float* __restrict__ out4d,
                         const int* __restrict__ sample,
                         float* __restrict__ P32,
                         unsigned short* __restrict__ XA,
                         unsigned short* __restrict__ XB,
                         unsigned* __restrict__ counter) {
    int idx = blockIdx.x * blockDim.x + threadIdx.x;   // 0 .. N*S*32-1
    if (idx == 0) counter[0] = 0u;                     // reset fused-final counter
    int lane = idx & 63;
    int hi   = lane >> 5;
    int l    = lane & 31;
    int ns = idx >> 5;
    int nn = ns >> 13;
    int s  = ns & (S - 1);
    int smp = sample[s];
    int row = smp / WC;
    int col = smp - row * WC;
    const float* base = out4d + ((size_t)nn * C) * H * W
                      + (size_t)(PADC + row) * W + (PADC + col);
    float v = 0.f;
    if (l < C) v = base[(size_t)l * (H * W)];
    unsigned hb = f2bf_rne(v);
    unsigned lb = f2bf_rne(v - bf2f((unsigned short)hb));

    if (l < CP) P32[(size_t)ns * CP + l] = v;          // l==19 writes 0

    int base32 = hi << 5;
    int srcA = base32 + (l < C ? l : l - C);           // channel l-19 for tail
    int srcB = base32 + (l < C ? l : l - 6);           // channel l-6  for tail
    unsigned lbA = (unsigned)__shfl((int)lb, srcA, 64);
    unsigned hbA = (unsigned)__shfl((int)hb, srcA, 64);
    unsigned lbB = (unsigned)__shfl((int)lb, srcB, 64);
    unsigned hbB = (unsigned)__shfl((int)hb, srcB, 64);

    unsigned short a0 = (unsigned short)(l < C ? hb : lbA);                   // slot I
    unsigned short a1 = (unsigned short)(l < C ? hb : (l < 25 ? lbB : 0u));   // slot II
    unsigned short b0 = (unsigned short)hbA;                                  // slot I
    unsigned short b1 = (unsigned short)(l < C ? lb : (l < 25 ? hbB : 0u));   // slot II

    unsigned short* xa = XA + (size_t)ns * XP;
    unsigned short* xb = XB + (size_t)ns * XP;
    xa[l]      = a0;
    xa[32 + l] = a1;
    xb[l]      = b0;
    xb[32 + l] = b1;
}

// per (n, 512-s-group, t-chunk): per-s best (quantized sim, earliest tile) as a
// packed u32 key. 4 waves/block; each wave owns FOUR 32-s tiles
// -> 16 MFMA per 4 ds_read_b128 (LDS pipe off the critical path).
__global__ __launch_bounds__(256, 3) void argmax_k(const unsigned short* __restrict__ XA,
                                                   const unsigned short* __restrict__ XB,
                                                   unsigned* __restrict__ keys) {
    __shared__ unsigned short lds[2][TTS * LPITCH];   // 2 x 18432 B
    int b = blockIdx.x;
    int chunk  = b & (NCHUNK - 1);
    int sgroup = (b >> 4) & 15;
    int nn     = b >> 8;
    int tid  = threadIdx.x;
    int w    = tid >> 6;              // wave 0..3
    int lane = tid & 63;
    int col  = lane & 31;
    int hi   = lane >> 5;
    int t0   = chunk * CHUNKT;
    const unsigned short* XAn = XA + (size_t)nn * S * XP;
    const unsigned short* XBn = XB + (size_t)nn * S * XP;

    // 4 B-sets per wave: s tiles sgroup*512 + (w*4+j)*32
    int sb[4];
    short8 bf[4][4];
    #pragma unroll
    for (int j = 0; j < 4; ++j) {
        sb[j] = sgroup * 512 + (w * 4 + j) * 32;
        const unsigned short* bp = XBn + (size_t)(sb[j] + col) * XP + hi * 8;
        bf[j][0] = *(const short8*)(bp);
        bf[j][1] = *(const short8*)(bp + 16);
        bf[j][2] = *(const short8*)(bp + 32);
        bf[j][3] = *(const short8*)(bp + 48);
    }

    f32x16 zacc = {};
    unsigned key[4] = {0u, 0u, 0u, 0u};

    {   // prologue: stage 0 -> buf0 (128 rows x 128 B = 1024 float4, 4/thread)
        const float4* src = (const float4*)(XAn + (size_t)t0 * XP);
        #pragma unroll
        for (int k = 0; k < 4; ++k) {
            int f = k * 256 + tid;
            *(float4*)(&lds[0][(f >> 3) * LPITCH + (f & 7) * 8]) = src[f];
        }
    }
    __syncthreads();

    int cur = 0;
    for (int st = 0; st < NSTG; ++st) {
        float4 nx[4];
        if (st + 1 < NSTG) {   // issue next-stage loads early
            const float4* srcn = (const float4*)(XAn + (size_t)(t0 + (st + 1) * TTS) * XP);
            #pragma unroll
            for (int k = 0; k < 4; ++k) nx[k] = srcn[k * 256 + tid];
        }
        const unsigned short* bs = &lds[cur][0];
        #pragma unroll
        for (int ts = 0; ts < TPS; ++ts) {
            const unsigned short* arow = bs + (ts * 32 + col) * LPITCH + hi * 8;
            short8 a0 = *(const short8*)(arow);
            short8 a1 = *(const short8*)(arow + 16);
            short8 a2 = *(const short8*)(arow + 32);
            short8 a3 = *(const short8*)(arow + 48);
            int tile = st * TPS + ts;              // [0,16)
            unsigned tb = (unsigned)(63 - tile);   // larger = earlier tile
            #pragma unroll
            for (int j = 0; j < 4; ++j) {
                f32x16 acc = __builtin_amdgcn_mfma_f32_32x32x16_bf16(a0, bf[j][0], zacc, 0, 0, 0);
                acc = __builtin_amdgcn_mfma_f32_32x32x16_bf16(a1, bf[j][1], acc, 0, 0, 0);
                acc = __builtin_amdgcn_mfma_f32_32x32x16_bf16(a2, bf[j][2], acc, 0, 0, 0);
                acc = __builtin_amdgcn_mfma_f32_32x32x16_bf16(a3, bf[j][3], acc, 0, 0, 0);
                unsigned v = (__float_as_uint(max16c(acc)) & ~63u) | tb;
                key[j] = key[j] > v ? key[j] : v;
            }
        }
        if (st + 1 < NSTG) {   // write other buffer after compute; 1 barrier/stage
            #pragma unroll
            for (int k = 0; k < 4; ++k) {
                int f = k * 256 + tid;
                *(float4*)(&lds[cur ^ 1][(f >> 3) * LPITCH + (f & 7) * 8]) = nx[k];
            }
        }
        __syncthreads();
        cur ^= 1;
    }

    size_t basek = ((size_t)nn * NCHUNK + chunk) * S;
    #pragma unroll
    for (int j = 0; j < 4; ++j) {
        unsigned o = __shfl(key[j], lane ^ 32, 64);
        unsigned k = key[j] > o ? key[j] : o;
        if (lane < 32) keys[basek + sb[j] + col] = k;
    }
}

// per s: merge chunk keys (earliest chunk on quantized ties), EXACT fp32 rescan
// of the winning 32-row tile (first-max), 19 loss terms, fixed-order reduce.
// Last block (counter) does the fixed-order final sum -> out[0].
__global__ __launch_bounds__(256) void refine_loss_k(const float* __restrict__ P32,
                                                     const unsigned* __restrict__ keys,
                                                     float* __restrict__ bsum,
                                                     unsigned* __restrict__ counter,
                                                     float* __restrict__ out) {
    __shared__ float red[8];
    __shared__ float fred[256];
    __shared__ unsigned rank;
    int tid = threadIdx.x;
    int lane = tid & 63;
    int hi = lane >> 5;
    int l  = lane & 31;
    int ns = blockIdx.x * 8 + (tid >> 6) * 2 + hi;   // 0 .. N*S-1
    int nn = ns >> 13;
    int s  = ns & (S - 1);

    const unsigned* kp = keys + (size_t)nn * NCHUNK * S + s;
    unsigned bk = kp[0]; int bc = 0;
    #pragma unroll
    for (int c = 1; c < NCHUNK; ++c) {
        unsigned k = kp[(size_t)c * S];
        if ((k >> 6) > (bk >> 6)) { bk = k; bc = c; }
    }
    int tile = 63 - (int)(bk & 63u);
    int tbase = bc * CHUNKT + tile * 32;

    const float* Pn = P32 + (size_t)nn * S * CP;
    const float* sr = Pn + (size_t)s * CP;
    const float* tr = Pn + (size_t)(tbase + l) * CP;
    float v = 0.f;
    #pragma unroll
    for (int c = 0; c < C; ++c) v = fmaf(sr[c], tr[c], v);
    int t = tbase + l;
    #pragma unroll
    for (int off = 16; off > 0; off >>= 1) {
        float ov = __shfl_xor(v, off, 32);
        int   ot = __shfl_xor(t, off, 32);
        if (ov > v || (ov == v && ot < t)) { v = ov; t = ot; }  // first-max
    }
    // all 32 lanes hold t*; lanes 0..18 each compute one loss term
    const float* nrow = Pn + (size_t)t * CP;
    float term = 0.f;
    if (l < C) term = -nrow[l] * logf(sr[l] + EPSF);
    #pragma unroll
    for (int off = 16; off > 0; off >>= 1)
        term += __shfl_xor(term, off, 32);
    if (l == 0) red[tid >> 5] = term;
    __syncthreads();
    if (tid == 0) {
        float a = 0.f;
        #pragma unroll
        for (int i = 0; i < 8; ++i) a += red[i];    // fixed order
        bsum[blockIdx.x] = a;
        __threadfence();                            // publish before count
        rank = atomicAdd(counter, 1u);
    }
    __syncthreads();
    if (rank == NBLK - 1) {
        // final fixed-order sum; atomic reads -> device-coherent (no stale L2)
        float a = 0.f;
        #pragma unroll
        for (int i = 0; i < NBLK / 256; ++i)
            a += atomicAdd(&bsum[i * 256 + tid], 0.f);
        fred[tid] = a;
        __syncthreads();
        for (int off = 128; off > 0; off >>= 1) {
            if (tid < off) fred[tid] += fred[tid + off];
            __syncthreads();
        }
        if (tid == 0) out[0] = fred[0] / (float)(N * S * C);
    }
}

extern "C" void kernel_launch(void* const* d_in, const int* in_sizes, int n_in,
                              void* d_out, int out_size, void* d_ws, size_t ws_size,
                              hipStream_t stream) {
    const float* out4d  = (const float*)d_in[0];
    const int*   sample = (const int*)d_in[1];

    float*          P32  = (float*)d_ws;                                // N*S*CP f32
    unsigned short* XA   = (unsigned short*)(P32 + (size_t)N * S * CP); // N*S*XP u16
    unsigned short* XB   = XA + (size_t)N * S * XP;                     // N*S*XP u16
    unsigned*       keys = (unsigned*)(XB + (size_t)N * S * XP);        // N*NCHUNK*S u32
    float*          bsum = (float*)(keys + (size_t)N * NCHUNK * S);     // NBLK f32
    unsigned*       ctr  = (unsigned*)(bsum + NBLK);                    // 1 u32
    float*          outp = (float*)d_out;

    gather_k<<<(N * S * 32) / 256, 256, 0, stream>>>(out4d, sample, P32, XA, XB, ctr);
    argmax_k<<<N * 16 * NCHUNK, 256, 0, stream>>>(XA, XB, keys);
    refine_loss_k<<<NBLK, 256, 0, stream>>>(P32, keys, bsum, ctr, outp);
}